// Round 1
// baseline (320.990 us; speedup 1.0000x reference)
//
#include <hip/hip_runtime.h>
#include <stdint.h>

#define B_SZ 2
#define T_SZ 2048
#define C_SZ 1024
#define NH   16
#define NKV  4
#define HD   64
#define KVD  256
#define QKV_N 1536

typedef __attribute__((ext_vector_type(8))) short bf16x8;
typedef __attribute__((ext_vector_type(4))) float f32x4;

__device__ inline unsigned short f2bf(float f) {
  union { float f; unsigned u; } v; v.f = f;
  unsigned u = v.u;
  unsigned r = (u + 0x7fffu + ((u >> 16) & 1u)) >> 16;
  return (unsigned short)r;
}

// ---------------- fp32 -> bf16 convert (vectorized x4) ----------------
__global__ __launch_bounds__(256) void cvt_f32_bf16(const float* __restrict__ src,
                                                    unsigned short* __restrict__ dst,
                                                    int n4) {
  int i = blockIdx.x * 256 + threadIdx.x;
  if (i >= n4) return;
  float4 f = ((const float4*)src)[i];
  ushort4 o;
  o.x = f2bf(f.x); o.y = f2bf(f.y); o.z = f2bf(f.z); o.w = f2bf(f.w);
  ((ushort4*)dst)[i] = o;
}

// ---------------- bf16 GEMM:  C[m,n] = sum_k A[m,k] * B[n,k]  (fp32 out) ----------------
#define BM 128
#define BN 128
#define BK 32
__global__ __launch_bounds__(256) void gemm_bt(const unsigned short* __restrict__ A,
                                               const unsigned short* __restrict__ Bm,
                                               float* __restrict__ C,
                                               int M, int N, int K) {
  __shared__ unsigned short As[BM * BK];
  __shared__ unsigned short Bs[BN * BK];
  int tid  = threadIdx.x;
  int lane = tid & 63;
  int wave = tid >> 6;
  int quad = lane >> 4;
  int l16  = lane & 15;
  int m0 = blockIdx.y * BM;
  int n0 = blockIdx.x * BN;
  int wm = (wave & 1) * 64;
  int wn = (wave >> 1) * 64;

  f32x4 acc[4][4];
#pragma unroll
  for (int i = 0; i < 4; i++)
#pragma unroll
    for (int j = 0; j < 4; j++) acc[i][j] = (f32x4){0.f, 0.f, 0.f, 0.f};

  int lr = tid >> 1;          // 0..127 (tile row)
  int lc = (tid & 1) * 16;    // 0 or 16 (col start, 16 elems per thread)

  for (int k0 = 0; k0 < K; k0 += BK) {
    const unsigned short* ap = &A[(size_t)(m0 + lr) * K + k0 + lc];
    const unsigned short* bp = &Bm[(size_t)(n0 + lr) * K + k0 + lc];
    uint4 a0 = *(const uint4*)(ap);
    uint4 a1 = *(const uint4*)(ap + 8);
    uint4 b0 = *(const uint4*)(bp);
    uint4 b1 = *(const uint4*)(bp + 8);
    *(uint4*)&As[lr * BK + lc]     = a0;
    *(uint4*)&As[lr * BK + lc + 8] = a1;
    *(uint4*)&Bs[lr * BK + lc]     = b0;
    *(uint4*)&Bs[lr * BK + lc + 8] = b1;
    __syncthreads();

    bf16x8 af[4], bfr[4];
#pragma unroll
    for (int i = 0; i < 4; i++)
      af[i] = *(const bf16x8*)&As[(wm + i * 16 + l16) * BK + quad * 8];
#pragma unroll
    for (int j = 0; j < 4; j++)
      bfr[j] = *(const bf16x8*)&Bs[(wn + j * 16 + l16) * BK + quad * 8];
#pragma unroll
    for (int i = 0; i < 4; i++)
#pragma unroll
      for (int j = 0; j < 4; j++)
        acc[i][j] = __builtin_amdgcn_mfma_f32_16x16x32_bf16(af[i], bfr[j], acc[i][j], 0, 0, 0);
    __syncthreads();
  }

#pragma unroll
  for (int i = 0; i < 4; i++) {
#pragma unroll
    for (int j = 0; j < 4; j++) {
      int col = n0 + wn + j * 16 + l16;
#pragma unroll
      for (int r = 0; r < 4; r++) {
        int row = m0 + wm + i * 16 + quad * 4 + r;
        C[(size_t)row * N + col] = acc[i][j][r];
      }
    }
  }
}

// ---------------- gate+ve, RoPE, RMSNorm, layout for attention ----------------
// qa: (B,NH,T,HD) bf16, pre-scaled by 1.2*0.125
// ka: (B,NKV,T,HD) bf16, pre-scaled by 1.2
// vt: (B,NKV,HD,T) bf16 (transposed for PV B-operand)
__global__ __launch_bounds__(256) void postproc(const float* __restrict__ qkv,
                                                const float* __restrict__ x,
                                                const float* __restrict__ ve,
                                                const float* __restrict__ cosb,
                                                const float* __restrict__ sinb,
                                                const float* __restrict__ Wg,
                                                unsigned short* __restrict__ qa,
                                                unsigned short* __restrict__ ka,
                                                unsigned short* __restrict__ vt) {
  int bt = blockIdx.x;
  int b = bt >> 11;
  int t = bt & 2047;
  int tid = threadIdx.x;
  __shared__ float row[QKV_N];
  __shared__ float gate[4];
  for (int i = tid; i < QKV_N; i += 256) row[i] = qkv[(size_t)bt * QKV_N + i];
  if (tid < 4) {
    float s = 0.f;
#pragma unroll
    for (int j = 0; j < 12; j++) s += x[(size_t)bt * C_SZ + j] * Wg[tid * 12 + j];
    gate[tid] = 3.f / (1.f + __expf(-s));
  }
  __syncthreads();

  int g = tid >> 3, sub = tid & 7;
  if (g < 20) {
    int off = (g < 16) ? g * 64 : 1024 + (g - 16) * 64;
    float o1[4], o2[4];
    float ssq = 0.f;
#pragma unroll
    for (int p = 0; p < 4; p++) {
      int j = sub * 4 + p;
      float cv = cosb[t * 32 + j];
      float sv = sinb[t * 32 + j];
      float a1 = row[off + j];
      float a2 = row[off + 32 + j];
      o1[p] = a1 * cv + a2 * sv;
      o2[p] = -a1 * sv + a2 * cv;
      ssq += o1[p] * o1[p] + o2[p] * o2[p];
    }
    ssq += __shfl_xor(ssq, 1);
    ssq += __shfl_xor(ssq, 2);
    ssq += __shfl_xor(ssq, 4);
    float rn = rsqrtf(ssq * (1.f / 64.f) + 1e-6f);
    rn *= (g < 16) ? (1.2f * 0.125f) : 1.2f;
    ushort4 w1, w2;
    w1.x = f2bf(o1[0] * rn); w1.y = f2bf(o1[1] * rn);
    w1.z = f2bf(o1[2] * rn); w1.w = f2bf(o1[3] * rn);
    w2.x = f2bf(o2[0] * rn); w2.y = f2bf(o2[1] * rn);
    w2.z = f2bf(o2[2] * rn); w2.w = f2bf(o2[3] * rn);
    if (g < 16) {
      size_t base = ((size_t)(b * NH + g) * T_SZ + t) * HD;
      *(ushort4*)&qa[base + sub * 4]      = w1;
      *(ushort4*)&qa[base + 32 + sub * 4] = w2;
    } else {
      size_t base = ((size_t)(b * NKV + (g - 16)) * T_SZ + t) * HD;
      *(ushort4*)&ka[base + sub * 4]      = w1;
      *(ushort4*)&ka[base + 32 + sub * 4] = w2;
    }
  }
  {
    int khh = tid >> 6, d = tid & 63;
    float val = row[1280 + tid] + gate[khh] * ve[(size_t)bt * KVD + tid];
    vt[((size_t)(b * NKV + khh) * HD + d) * T_SZ + t] = f2bf(val);
  }
}

// ---------------- causal flash attention, Q-tile=64, 4 waves x 16 rows ----------------
__global__ __launch_bounds__(256) void attn(const unsigned short* __restrict__ qa,
                                            const unsigned short* __restrict__ ka,
                                            const unsigned short* __restrict__ vt,
                                            unsigned short* __restrict__ y) {
  int qt = blockIdx.x;   // 0..T/64-1
  int bh = blockIdx.y;   // 0..B*NH-1
  int b = bh >> 4, h = bh & 15;
  int kh = h >> 2;
  int tid = threadIdx.x;
  int wave = tid >> 6, lane = tid & 63;
  int quad = lane >> 4, l16 = lane & 15;

  __shared__ unsigned short Ks[64 * 64];
  __shared__ unsigned short Vs[64 * 64];
  __shared__ unsigned short Ps[4 * 16 * 64];

  bf16x8 aq[2];
  {
    int tq = qt * 64 + wave * 16 + l16;
    const unsigned short* qp = &qa[((size_t)(b * NH + h) * T_SZ + tq) * HD];
    aq[0] = *(const bf16x8*)&qp[quad * 8];
    aq[1] = *(const bf16x8*)&qp[32 + quad * 8];
  }

  float m_i[4], l_i[4];
  f32x4 oacc[4];
#pragma unroll
  for (int i = 0; i < 4; i++) { m_i[i] = -__builtin_inff(); l_i[i] = 0.f; }
#pragma unroll
  for (int d = 0; d < 4; d++) oacc[d] = (f32x4){0.f, 0.f, 0.f, 0.f};

  int lr = tid >> 2;          // 0..63
  int lc = (tid & 3) * 16;    // 0,16,32,48

  const unsigned short* kbase = &ka[(size_t)(b * NKV + kh) * T_SZ * HD];
  const unsigned short* vbase = &vt[(size_t)(b * NKV + kh) * HD * T_SZ];

  for (int j = 0; j <= qt; j++) {
    __syncthreads();  // protect LDS from previous iteration's readers
    {
      const unsigned short* kp = &kbase[(size_t)(j * 64 + lr) * HD + lc];
      const unsigned short* vp = &vbase[(size_t)lr * T_SZ + j * 64 + lc];
      uint4 k0 = *(const uint4*)(kp);
      uint4 k1 = *(const uint4*)(kp + 8);
      uint4 v0 = *(const uint4*)(vp);
      uint4 v1 = *(const uint4*)(vp + 8);
      *(uint4*)&Ks[lr * 64 + lc]     = k0;
      *(uint4*)&Ks[lr * 64 + lc + 8] = k1;
      *(uint4*)&Vs[lr * 64 + lc]     = v0;
      *(uint4*)&Vs[lr * 64 + lc + 8] = v1;
    }
    __syncthreads();

    // S = Q K^T (scale pre-folded into q)
    f32x4 sa[4];
#pragma unroll
    for (int nb = 0; nb < 4; nb++) {
      bf16x8 bk0 = *(const bf16x8*)&Ks[(nb * 16 + l16) * 64 + quad * 8];
      bf16x8 bk1 = *(const bf16x8*)&Ks[(nb * 16 + l16) * 64 + 32 + quad * 8];
      f32x4 s = (f32x4){0.f, 0.f, 0.f, 0.f};
      s = __builtin_amdgcn_mfma_f32_16x16x32_bf16(aq[0], bk0, s, 0, 0, 0);
      s = __builtin_amdgcn_mfma_f32_16x16x32_bf16(aq[1], bk1, s, 0, 0, 0);
      sa[nb] = s;
    }

    if (j == qt) {  // causal mask on diagonal tile
#pragma unroll
      for (int nb = 0; nb < 4; nb++) {
        int kcol = nb * 16 + l16;
#pragma unroll
        for (int i = 0; i < 4; i++) {
          if (kcol > wave * 16 + quad * 4 + i) sa[nb][i] = -__builtin_inff();
        }
      }
    }

    // online softmax (rows quad*4+i, reduced over the 16-lane group)
#pragma unroll
    for (int i = 0; i < 4; i++) {
      float mx = fmaxf(fmaxf(sa[0][i], sa[1][i]), fmaxf(sa[2][i], sa[3][i]));
      mx = fmaxf(mx, __shfl_xor(mx, 1));
      mx = fmaxf(mx, __shfl_xor(mx, 2));
      mx = fmaxf(mx, __shfl_xor(mx, 4));
      mx = fmaxf(mx, __shfl_xor(mx, 8));
      float mn = fmaxf(m_i[i], mx);
      float alpha = __expf(m_i[i] - mn);
      m_i[i] = mn;
      float rs = 0.f;
#pragma unroll
      for (int nb = 0; nb < 4; nb++) {
        float pv = __expf(sa[nb][i] - mn);
        sa[nb][i] = pv;
        rs += pv;
      }
      rs += __shfl_xor(rs, 1);
      rs += __shfl_xor(rs, 2);
      rs += __shfl_xor(rs, 4);
      rs += __shfl_xor(rs, 8);
      l_i[i] = l_i[i] * alpha + rs;
#pragma unroll
      for (int d = 0; d < 4; d++) oacc[d][i] *= alpha;
    }

    // P: C-layout -> LDS -> A-layout
#pragma unroll
    for (int nb = 0; nb < 4; nb++)
#pragma unroll
      for (int i = 0; i < 4; i++)
        Ps[wave * 1024 + (quad * 4 + i) * 64 + nb * 16 + l16] = f2bf(sa[nb][i]);
    __syncthreads();

    bf16x8 ap0 = *(const bf16x8*)&Ps[wave * 1024 + l16 * 64 + quad * 8];
    bf16x8 ap1 = *(const bf16x8*)&Ps[wave * 1024 + l16 * 64 + 32 + quad * 8];
#pragma unroll
    for (int d = 0; d < 4; d++) {
      bf16x8 bv0 = *(const bf16x8*)&Vs[(d * 16 + l16) * 64 + quad * 8];
      bf16x8 bv1 = *(const bf16x8*)&Vs[(d * 16 + l16) * 64 + 32 + quad * 8];
      oacc[d] = __builtin_amdgcn_mfma_f32_16x16x32_bf16(ap0, bv0, oacc[d], 0, 0, 0);
      oacc[d] = __builtin_amdgcn_mfma_f32_16x16x32_bf16(ap1, bv1, oacc[d], 0, 0, 0);
    }
  }

  // epilogue: y[(b,t),(h*64+d)] bf16
#pragma unroll
  for (int i = 0; i < 4; i++) {
    int tq = qt * 64 + wave * 16 + quad * 4 + i;
    float inv = 1.f / l_i[i];
#pragma unroll
    for (int d = 0; d < 4; d++) {
      y[((size_t)(b * T_SZ) + tq) * C_SZ + h * HD + d * 16 + l16] = f2bf(oacc[d][i] * inv);
    }
  }
}

extern "C" void kernel_launch(void* const* d_in, const int* in_sizes, int n_in,
                              void* d_out, int out_size, void* d_ws, size_t ws_size,
                              hipStream_t stream) {
  const float* x    = (const float*)d_in[0];
  const float* ve   = (const float*)d_in[1];
  const float* cosb = (const float*)d_in[2];
  const float* sinb = (const float*)d_in[3];
  const float* Wq   = (const float*)d_in[4];
  const float* Wk   = (const float*)d_in[5];
  const float* Wv   = (const float*)d_in[6];
  const float* Wo   = (const float*)d_in[7];
  const float* Wg   = (const float*)d_in[8];
  float* out = (float*)d_out;

  const size_t MB = 1024 * 1024;
  char* ws = (char*)d_ws;
  unsigned short* xb    = (unsigned short*)(ws);             // 8 MB (reused as yb later)
  unsigned short* wqkvb = (unsigned short*)(ws + 8 * MB);    // 3 MB
  unsigned short* wob   = (unsigned short*)(ws + 11 * MB);   // 2 MB
  float*          qkvf  = (float*)(ws + 13 * MB);            // 24 MB -> ends at 37 MB
  unsigned short* qab   = (unsigned short*)(ws + 37 * MB);   // 8 MB
  unsigned short* kab   = (unsigned short*)(ws + 45 * MB);   // 2 MB
  unsigned short* vtb   = (unsigned short*)(ws + 47 * MB);   // 2 MB -> 49 MB total
  unsigned short* yb    = xb;                                // reuse after gemm1

  auto cvt = [&](const float* s, unsigned short* d, int n) {
    int n4 = n / 4;
    cvt_f32_bf16<<<(n4 + 255) / 256, 256, 0, stream>>>(s, d, n4);
  };
  cvt(x,  xb,                 B_SZ * T_SZ * C_SZ);
  cvt(Wq, wqkvb,              C_SZ * C_SZ);
  cvt(Wk, wqkvb + 1024 * 1024, KVD * C_SZ);
  cvt(Wv, wqkvb + 1280 * 1024, KVD * C_SZ);
  cvt(Wo, wob,                C_SZ * C_SZ);

  gemm_bt<<<dim3(QKV_N / BN, (B_SZ * T_SZ) / BM), 256, 0, stream>>>(
      xb, wqkvb, qkvf, B_SZ * T_SZ, QKV_N, C_SZ);

  postproc<<<B_SZ * T_SZ, 256, 0, stream>>>(qkvf, x, ve, cosb, sinb, Wg, qab, kab, vtb);

  attn<<<dim3(T_SZ / 64, B_SZ * NH), 256, 0, stream>>>(qab, kab, vtb, yb);

  // out = y @ Wo^T ; but gemm writes fp32 C directly into d_out
  gemm_bt<<<dim3(C_SZ / BN, (B_SZ * T_SZ) / BM), 256, 0, stream>>>(
      yb, wob, out, B_SZ * T_SZ, C_SZ, C_SZ);
}

// Round 2
// 264.424 us; speedup vs baseline: 1.2139x; 1.2139x over previous
//
#include <hip/hip_runtime.h>
#include <stdint.h>

#define B_SZ 2
#define T_SZ 2048
#define C_SZ 1024
#define NH   16
#define NKV  4
#define HD   64
#define KVD  256
#define QKV_N 1536

typedef __attribute__((ext_vector_type(8))) short bf16x8;
typedef __attribute__((ext_vector_type(4))) float f32x4;

__device__ inline unsigned short f2bf(float f) {
  union { float f; unsigned u; } v; v.f = f;
  unsigned u = v.u;
  unsigned r = (u + 0x7fffu + ((u >> 16) & 1u)) >> 16;
  return (unsigned short)r;
}

// ---------------- fp32 -> bf16 convert (vectorized x4) ----------------
__global__ __launch_bounds__(256) void cvt_f32_bf16(const float* __restrict__ src,
                                                    unsigned short* __restrict__ dst,
                                                    int n4) {
  int i = blockIdx.x * 256 + threadIdx.x;
  if (i >= n4) return;
  float4 f = ((const float4*)src)[i];
  ushort4 o;
  o.x = f2bf(f.x); o.y = f2bf(f.y); o.z = f2bf(f.z); o.w = f2bf(f.w);
  ((ushort4*)dst)[i] = o;
}

// ---------------- bf16 GEMM:  C[m,n] = sum_k A[m,k] * B[n,k]  (fp32 out) ----------------
#define BM 128
#define BN 128
#define BK 32
#define ASTR 40   // padded stride (shorts): 80 B -> conflict-free b128 frag reads
__global__ __launch_bounds__(256) void gemm_bt(const unsigned short* __restrict__ A,
                                               const unsigned short* __restrict__ Bm,
                                               float* __restrict__ C,
                                               int M, int N, int K) {
  __shared__ unsigned short As[BM * ASTR];
  __shared__ unsigned short Bs[BN * ASTR];
  int tid  = threadIdx.x;
  int lane = tid & 63;
  int wave = tid >> 6;
  int quad = lane >> 4;
  int l16  = lane & 15;
  int m0 = blockIdx.y * BM;
  int n0 = blockIdx.x * BN;
  int wm = (wave & 1) * 64;
  int wn = (wave >> 1) * 64;

  f32x4 acc[4][4];
#pragma unroll
  for (int i = 0; i < 4; i++)
#pragma unroll
    for (int j = 0; j < 4; j++) acc[i][j] = (f32x4){0.f, 0.f, 0.f, 0.f};

  int lr = tid >> 1;          // 0..127 (tile row)
  int lc = (tid & 1) * 16;    // 0 or 16 (col start, 16 elems per thread)

  // register prefetch of tile 0
  const unsigned short* ap = &A[(size_t)(m0 + lr) * K + lc];
  const unsigned short* bp = &Bm[(size_t)(n0 + lr) * K + lc];
  uint4 a0 = *(const uint4*)(ap);
  uint4 a1 = *(const uint4*)(ap + 8);
  uint4 b0 = *(const uint4*)(bp);
  uint4 b1 = *(const uint4*)(bp + 8);

  for (int k0 = 0; k0 < K; k0 += BK) {
    __syncthreads();
    *(uint4*)&As[lr * ASTR + lc]     = a0;
    *(uint4*)&As[lr * ASTR + lc + 8] = a1;
    *(uint4*)&Bs[lr * ASTR + lc]     = b0;
    *(uint4*)&Bs[lr * ASTR + lc + 8] = b1;
    if (k0 + BK < K) {
      const unsigned short* ap2 = &A[(size_t)(m0 + lr) * K + k0 + BK + lc];
      const unsigned short* bp2 = &Bm[(size_t)(n0 + lr) * K + k0 + BK + lc];
      a0 = *(const uint4*)(ap2);
      a1 = *(const uint4*)(ap2 + 8);
      b0 = *(const uint4*)(bp2);
      b1 = *(const uint4*)(bp2 + 8);
    }
    __syncthreads();

    bf16x8 af[4], bfr[4];
#pragma unroll
    for (int i = 0; i < 4; i++)
      af[i] = *(const bf16x8*)&As[(wm + i * 16 + l16) * ASTR + quad * 8];
#pragma unroll
    for (int j = 0; j < 4; j++)
      bfr[j] = *(const bf16x8*)&Bs[(wn + j * 16 + l16) * ASTR + quad * 8];
#pragma unroll
    for (int i = 0; i < 4; i++)
#pragma unroll
      for (int j = 0; j < 4; j++)
        acc[i][j] = __builtin_amdgcn_mfma_f32_16x16x32_bf16(af[i], bfr[j], acc[i][j], 0, 0, 0);
  }

#pragma unroll
  for (int i = 0; i < 4; i++) {
#pragma unroll
    for (int j = 0; j < 4; j++) {
      int col = n0 + wn + j * 16 + l16;
#pragma unroll
      for (int r = 0; r < 4; r++) {
        int row = m0 + wm + i * 16 + quad * 4 + r;
        C[(size_t)row * N + col] = acc[i][j][r];
      }
    }
  }
}

// ---------------- gate+ve, RoPE, RMSNorm, layout for attention ----------------
__global__ __launch_bounds__(256) void postproc(const float* __restrict__ qkv,
                                                const float* __restrict__ x,
                                                const float* __restrict__ ve,
                                                const float* __restrict__ cosb,
                                                const float* __restrict__ sinb,
                                                const float* __restrict__ Wg,
                                                unsigned short* __restrict__ qa,
                                                unsigned short* __restrict__ ka,
                                                unsigned short* __restrict__ vt) {
  int bt = blockIdx.x;
  int b = bt >> 11;
  int t = bt & 2047;
  int tid = threadIdx.x;
  __shared__ float row[QKV_N];
  __shared__ float gate[4];
  for (int i = tid; i < QKV_N; i += 256) row[i] = qkv[(size_t)bt * QKV_N + i];
  if (tid < 4) {
    float s = 0.f;
#pragma unroll
    for (int j = 0; j < 12; j++) s += x[(size_t)bt * C_SZ + j] * Wg[tid * 12 + j];
    gate[tid] = 3.f / (1.f + __expf(-s));
  }
  __syncthreads();

  int g = tid >> 3, sub = tid & 7;
  if (g < 20) {
    int off = (g < 16) ? g * 64 : 1024 + (g - 16) * 64;
    float o1[4], o2[4];
    float ssq = 0.f;
#pragma unroll
    for (int p = 0; p < 4; p++) {
      int j = sub * 4 + p;
      float cv = cosb[t * 32 + j];
      float sv = sinb[t * 32 + j];
      float a1 = row[off + j];
      float a2 = row[off + 32 + j];
      o1[p] = a1 * cv + a2 * sv;
      o2[p] = -a1 * sv + a2 * cv;
      ssq += o1[p] * o1[p] + o2[p] * o2[p];
    }
    ssq += __shfl_xor(ssq, 1);
    ssq += __shfl_xor(ssq, 2);
    ssq += __shfl_xor(ssq, 4);
    float rn = rsqrtf(ssq * (1.f / 64.f) + 1e-6f);
    rn *= (g < 16) ? (1.2f * 0.125f) : 1.2f;
    ushort4 w1, w2;
    w1.x = f2bf(o1[0] * rn); w1.y = f2bf(o1[1] * rn);
    w1.z = f2bf(o1[2] * rn); w1.w = f2bf(o1[3] * rn);
    w2.x = f2bf(o2[0] * rn); w2.y = f2bf(o2[1] * rn);
    w2.z = f2bf(o2[2] * rn); w2.w = f2bf(o2[3] * rn);
    if (g < 16) {
      size_t base = ((size_t)(b * NH + g) * T_SZ + t) * HD;
      *(ushort4*)&qa[base + sub * 4]      = w1;
      *(ushort4*)&qa[base + 32 + sub * 4] = w2;
    } else {
      size_t base = ((size_t)(b * NKV + (g - 16)) * T_SZ + t) * HD;
      *(ushort4*)&ka[base + sub * 4]      = w1;
      *(ushort4*)&ka[base + 32 + sub * 4] = w2;
    }
  }
  {
    int khh = tid >> 6, d = tid & 63;
    float val = row[1280 + tid] + gate[khh] * ve[(size_t)bt * KVD + tid];
    vt[((size_t)(b * NKV + khh) * HD + d) * T_SZ + t] = f2bf(val);
  }
}

// ---------------- causal flash attention, Q-tile=64, 4 waves x 16 rows ----------------
#define KSTR 72   // padded LDS row stride (shorts): 144 B, 16B-aligned, conflict-free b128
__global__ __launch_bounds__(256) void attn(const unsigned short* __restrict__ qa,
                                            const unsigned short* __restrict__ ka,
                                            const unsigned short* __restrict__ vt,
                                            unsigned short* __restrict__ y) {
  int qt = (gridDim.x - 1) - blockIdx.x;   // heavy tiles dispatch first
  int bh = blockIdx.y;
  int b = bh >> 4, h = bh & 15;
  int kh = h >> 2;
  int tid = threadIdx.x;
  int wave = tid >> 6, lane = tid & 63;
  int quad = lane >> 4, l16 = lane & 15;

  __shared__ unsigned short Ks[64 * KSTR];
  __shared__ unsigned short Vs[64 * KSTR];
  __shared__ unsigned short Ps[4 * 16 * KSTR];
  unsigned short* Pw = &Ps[wave * 16 * KSTR];

  bf16x8 aq[2];
  {
    int tq = qt * 64 + wave * 16 + l16;
    const unsigned short* qp = &qa[((size_t)(b * NH + h) * T_SZ + tq) * HD];
    aq[0] = *(const bf16x8*)&qp[quad * 8];
    aq[1] = *(const bf16x8*)&qp[32 + quad * 8];
  }

  float m_i[4], l_i[4];
  f32x4 oacc[4];
#pragma unroll
  for (int i = 0; i < 4; i++) { m_i[i] = -__builtin_inff(); l_i[i] = 0.f; }
#pragma unroll
  for (int d = 0; d < 4; d++) oacc[d] = (f32x4){0.f, 0.f, 0.f, 0.f};

  int lr = tid >> 2;          // 0..63
  int lc = (tid & 3) * 16;    // 0,16,32,48

  const unsigned short* kbase = &ka[(size_t)(b * NKV + kh) * T_SZ * HD];
  const unsigned short* vbase = &vt[(size_t)(b * NKV + kh) * HD * T_SZ];

  // register prefetch of K/V tile 0
  uint4 k0, k1, v0, v1;
  {
    const unsigned short* kp = &kbase[(size_t)lr * HD + lc];
    const unsigned short* vp = &vbase[(size_t)lr * T_SZ + lc];
    k0 = *(const uint4*)(kp);
    k1 = *(const uint4*)(kp + 8);
    v0 = *(const uint4*)(vp);
    v1 = *(const uint4*)(vp + 8);
  }

  for (int j = 0; j <= qt; j++) {
    __syncthreads();  // previous iteration's readers done with Ks/Vs
    *(uint4*)&Ks[lr * KSTR + lc]     = k0;
    *(uint4*)&Ks[lr * KSTR + lc + 8] = k1;
    *(uint4*)&Vs[lr * KSTR + lc]     = v0;
    *(uint4*)&Vs[lr * KSTR + lc + 8] = v1;
    if (j < qt) {  // prefetch next tile; latency hidden behind this tile's compute
      const unsigned short* kp = &kbase[(size_t)((j + 1) * 64 + lr) * HD + lc];
      const unsigned short* vp = &vbase[(size_t)lr * T_SZ + (j + 1) * 64 + lc];
      k0 = *(const uint4*)(kp);
      k1 = *(const uint4*)(kp + 8);
      v0 = *(const uint4*)(vp);
      v1 = *(const uint4*)(vp + 8);
    }
    __syncthreads();

    // S = Q K^T (scale pre-folded into q)
    f32x4 sa[4];
#pragma unroll
    for (int nb = 0; nb < 4; nb++) {
      bf16x8 bk0 = *(const bf16x8*)&Ks[(nb * 16 + l16) * KSTR + quad * 8];
      bf16x8 bk1 = *(const bf16x8*)&Ks[(nb * 16 + l16) * KSTR + 32 + quad * 8];
      f32x4 s = (f32x4){0.f, 0.f, 0.f, 0.f};
      s = __builtin_amdgcn_mfma_f32_16x16x32_bf16(aq[0], bk0, s, 0, 0, 0);
      s = __builtin_amdgcn_mfma_f32_16x16x32_bf16(aq[1], bk1, s, 0, 0, 0);
      sa[nb] = s;
    }

    if (j == qt) {  // causal mask on diagonal tile
#pragma unroll
      for (int nb = 0; nb < 4; nb++) {
        int kcol = nb * 16 + l16;
#pragma unroll
        for (int i = 0; i < 4; i++) {
          if (kcol > wave * 16 + quad * 4 + i) sa[nb][i] = -__builtin_inff();
        }
      }
    }

    // online softmax (rows quad*4+i, reduced over the 16-lane group)
#pragma unroll
    for (int i = 0; i < 4; i++) {
      float mx = fmaxf(fmaxf(sa[0][i], sa[1][i]), fmaxf(sa[2][i], sa[3][i]));
      mx = fmaxf(mx, __shfl_xor(mx, 1));
      mx = fmaxf(mx, __shfl_xor(mx, 2));
      mx = fmaxf(mx, __shfl_xor(mx, 4));
      mx = fmaxf(mx, __shfl_xor(mx, 8));
      float mn = fmaxf(m_i[i], mx);
      float alpha = __expf(m_i[i] - mn);
      m_i[i] = mn;
      float rs = 0.f;
#pragma unroll
      for (int nb = 0; nb < 4; nb++) {
        float pv = __expf(sa[nb][i] - mn);
        sa[nb][i] = pv;
        rs += pv;
      }
      rs += __shfl_xor(rs, 1);
      rs += __shfl_xor(rs, 2);
      rs += __shfl_xor(rs, 4);
      rs += __shfl_xor(rs, 8);
      l_i[i] = l_i[i] * alpha + rs;
#pragma unroll
      for (int d = 0; d < 4; d++) oacc[d][i] *= alpha;
    }

    // P: C-layout -> per-wave LDS region -> A-layout (no barrier needed:
    // same wave writes and reads its own region, LDS ops in-order via lgkmcnt)
#pragma unroll
    for (int nb = 0; nb < 4; nb++)
#pragma unroll
      for (int i = 0; i < 4; i++)
        Pw[(quad * 4 + i) * KSTR + nb * 16 + l16] = f2bf(sa[nb][i]);

    bf16x8 ap0 = *(const bf16x8*)&Pw[l16 * KSTR + quad * 8];
    bf16x8 ap1 = *(const bf16x8*)&Pw[l16 * KSTR + 32 + quad * 8];
#pragma unroll
    for (int d = 0; d < 4; d++) {
      bf16x8 bv0 = *(const bf16x8*)&Vs[(d * 16 + l16) * KSTR + quad * 8];
      bf16x8 bv1 = *(const bf16x8*)&Vs[(d * 16 + l16) * KSTR + 32 + quad * 8];
      oacc[d] = __builtin_amdgcn_mfma_f32_16x16x32_bf16(ap0, bv0, oacc[d], 0, 0, 0);
      oacc[d] = __builtin_amdgcn_mfma_f32_16x16x32_bf16(ap1, bv1, oacc[d], 0, 0, 0);
    }
  }

  // epilogue: y[(b,t),(h*64+d)] bf16
#pragma unroll
  for (int i = 0; i < 4; i++) {
    int tq = qt * 64 + wave * 16 + quad * 4 + i;
    float inv = 1.f / l_i[i];
#pragma unroll
    for (int d = 0; d < 4; d++) {
      y[((size_t)(b * T_SZ) + tq) * C_SZ + h * HD + d * 16 + l16] = f2bf(oacc[d][i] * inv);
    }
  }
}

extern "C" void kernel_launch(void* const* d_in, const int* in_sizes, int n_in,
                              void* d_out, int out_size, void* d_ws, size_t ws_size,
                              hipStream_t stream) {
  const float* x    = (const float*)d_in[0];
  const float* ve   = (const float*)d_in[1];
  const float* cosb = (const float*)d_in[2];
  const float* sinb = (const float*)d_in[3];
  const float* Wq   = (const float*)d_in[4];
  const float* Wk   = (const float*)d_in[5];
  const float* Wv   = (const float*)d_in[6];
  const float* Wo   = (const float*)d_in[7];
  const float* Wg   = (const float*)d_in[8];
  float* out = (float*)d_out;

  const size_t MB = 1024 * 1024;
  char* ws = (char*)d_ws;
  unsigned short* xb    = (unsigned short*)(ws);             // 8 MB (reused as yb later)
  unsigned short* wqkvb = (unsigned short*)(ws + 8 * MB);    // 3 MB
  unsigned short* wob   = (unsigned short*)(ws + 11 * MB);   // 2 MB
  float*          qkvf  = (float*)(ws + 13 * MB);            // 24 MB -> ends at 37 MB
  unsigned short* qab   = (unsigned short*)(ws + 37 * MB);   // 8 MB
  unsigned short* kab   = (unsigned short*)(ws + 45 * MB);   // 2 MB
  unsigned short* vtb   = (unsigned short*)(ws + 47 * MB);   // 2 MB -> 49 MB total
  unsigned short* yb    = xb;                                // reuse after gemm1

  auto cvt = [&](const float* s, unsigned short* d, int n) {
    int n4 = n / 4;
    cvt_f32_bf16<<<(n4 + 255) / 256, 256, 0, stream>>>(s, d, n4);
  };
  cvt(x,  xb,                 B_SZ * T_SZ * C_SZ);
  cvt(Wq, wqkvb,              C_SZ * C_SZ);
  cvt(Wk, wqkvb + 1024 * 1024, KVD * C_SZ);
  cvt(Wv, wqkvb + 1280 * 1024, KVD * C_SZ);
  cvt(Wo, wob,                C_SZ * C_SZ);

  gemm_bt<<<dim3(QKV_N / BN, (B_SZ * T_SZ) / BM), 256, 0, stream>>>(
      xb, wqkvb, qkvf, B_SZ * T_SZ, QKV_N, C_SZ);

  postproc<<<B_SZ * T_SZ, 256, 0, stream>>>(qkvf, x, ve, cosb, sinb, Wg, qab, kab, vtb);

  attn<<<dim3(T_SZ / 64, B_SZ * NH), 256, 0, stream>>>(qab, kab, vtb, yb);

  gemm_bt<<<dim3(C_SZ / BN, (B_SZ * T_SZ) / BM), 256, 0, stream>>>(
      yb, wob, out, B_SZ * T_SZ, C_SZ, C_SZ);
}

// Round 3
// 234.417 us; speedup vs baseline: 1.3693x; 1.1280x over previous
//
#include <hip/hip_runtime.h>
#include <stdint.h>

#define B_SZ 2
#define T_SZ 2048
#define C_SZ 1024
#define NH   16
#define NKV  4
#define HD   64
#define KVD  256
#define QKV_N 1536

typedef __attribute__((ext_vector_type(8))) short bf16x8;
typedef __attribute__((ext_vector_type(4))) float f32x4;

#define GL(p) ((const __attribute__((address_space(1))) void*)(p))
#define LD(p) ((__attribute__((address_space(3))) void*)(p))

__device__ inline unsigned short f2bf(float f) {
  union { float f; unsigned u; } v; v.f = f;
  unsigned u = v.u;
  unsigned r = (u + 0x7fffu + ((u >> 16) & 1u)) >> 16;
  return (unsigned short)r;
}

// ---------------- fp32 -> bf16 convert (vectorized x4) ----------------
__global__ __launch_bounds__(256) void cvt_f32_bf16(const float* __restrict__ src,
                                                    unsigned short* __restrict__ dst,
                                                    int n4) {
  int i = blockIdx.x * 256 + threadIdx.x;
  if (i >= n4) return;
  float4 f = ((const float4*)src)[i];
  ushort4 o;
  o.x = f2bf(f.x); o.y = f2bf(f.y); o.z = f2bf(f.z); o.w = f2bf(f.w);
  ((ushort4*)dst)[i] = o;
}

// ---------------- bf16 GEMM (m97 pattern):  C[m,n] = sum_k A[m,k]*B[n,k] ----------------
#define BM 128
#define BN 128
#define BK 32
__global__ __launch_bounds__(256) void gemm_bt(const unsigned short* __restrict__ A,
                                               const unsigned short* __restrict__ Bm,
                                               float* __restrict__ C,
                                               int M, int N, int K) {
  __shared__ unsigned short As[BM * BK];   // unpadded: required by global_load_lds
  __shared__ unsigned short Bs[BN * BK];
  int tid  = threadIdx.x;
  int lane = tid & 63;
  int wave = tid >> 6;
  int quad = lane >> 4;
  int l16  = lane & 15;
  int m0 = blockIdx.y * BM;
  int n0 = blockIdx.x * BN;
  int wm = (wave & 1) * 64;
  int wn = (wave >> 1) * 64;

  f32x4 acc[4][4];
#pragma unroll
  for (int i = 0; i < 4; i++)
#pragma unroll
    for (int j = 0; j < 4; j++) acc[i][j] = (f32x4){0.f, 0.f, 0.f, 0.f};

  // staging: wave w owns tile rows w*32..w*32+31; lane i -> row +(i>>2), col8 (i&3)*8
  int srow = wave * 32;
  int lrow = lane >> 2;
  int lcol = (lane & 3) * 8;
  const unsigned short* a0 = &A[(size_t)(m0 + srow + lrow) * K + lcol];
  const unsigned short* a1 = a0 + 16 * (size_t)K;
  const unsigned short* b0 = &Bm[(size_t)(n0 + srow + lrow) * K + lcol];
  const unsigned short* b1 = b0 + 16 * (size_t)K;
  unsigned short* lA0 = &As[srow * BK];
  unsigned short* lA1 = &As[(srow + 16) * BK];
  unsigned short* lB0 = &Bs[srow * BK];
  unsigned short* lB1 = &Bs[(srow + 16) * BK];

  for (int k0 = 0; k0 < K; k0 += BK) {
    __syncthreads();
    __builtin_amdgcn_global_load_lds(GL(a0 + k0), LD(lA0), 16, 0, 0);
    __builtin_amdgcn_global_load_lds(GL(a1 + k0), LD(lA1), 16, 0, 0);
    __builtin_amdgcn_global_load_lds(GL(b0 + k0), LD(lB0), 16, 0, 0);
    __builtin_amdgcn_global_load_lds(GL(b1 + k0), LD(lB1), 16, 0, 0);
    __syncthreads();

    bf16x8 af[4], bfr[4];
#pragma unroll
    for (int i = 0; i < 4; i++)
      af[i] = *(const bf16x8*)&As[(wm + i * 16 + l16) * BK + quad * 8];
#pragma unroll
    for (int j = 0; j < 4; j++)
      bfr[j] = *(const bf16x8*)&Bs[(wn + j * 16 + l16) * BK + quad * 8];
#pragma unroll
    for (int i = 0; i < 4; i++)
#pragma unroll
      for (int j = 0; j < 4; j++)
        acc[i][j] = __builtin_amdgcn_mfma_f32_16x16x32_bf16(af[i], bfr[j], acc[i][j], 0, 0, 0);
  }

#pragma unroll
  for (int i = 0; i < 4; i++) {
#pragma unroll
    for (int j = 0; j < 4; j++) {
      int col = n0 + wn + j * 16 + l16;
#pragma unroll
      for (int r = 0; r < 4; r++) {
        int row = m0 + wm + i * 16 + quad * 4 + r;
        C[(size_t)row * N + col] = acc[i][j][r];
      }
    }
  }
}

// ---------------- gate+ve, RoPE, RMSNorm, layout for attention ----------------
__global__ __launch_bounds__(256) void postproc(const float* __restrict__ qkv,
                                                const float* __restrict__ x,
                                                const float* __restrict__ ve,
                                                const float* __restrict__ cosb,
                                                const float* __restrict__ sinb,
                                                const float* __restrict__ Wg,
                                                unsigned short* __restrict__ qa,
                                                unsigned short* __restrict__ ka,
                                                unsigned short* __restrict__ vt) {
  int bt = blockIdx.x;
  int b = bt >> 11;
  int t = bt & 2047;
  int tid = threadIdx.x;
  __shared__ float row[QKV_N];
  __shared__ float gate[4];
  for (int i = tid; i < QKV_N; i += 256) row[i] = qkv[(size_t)bt * QKV_N + i];
  if (tid < 4) {
    float s = 0.f;
#pragma unroll
    for (int j = 0; j < 12; j++) s += x[(size_t)bt * C_SZ + j] * Wg[tid * 12 + j];
    gate[tid] = 3.f / (1.f + __expf(-s));
  }
  __syncthreads();

  int g = tid >> 3, sub = tid & 7;
  if (g < 20) {
    int off = (g < 16) ? g * 64 : 1024 + (g - 16) * 64;
    float o1[4], o2[4];
    float ssq = 0.f;
#pragma unroll
    for (int p = 0; p < 4; p++) {
      int j = sub * 4 + p;
      float cv = cosb[t * 32 + j];
      float sv = sinb[t * 32 + j];
      float a1 = row[off + j];
      float a2 = row[off + 32 + j];
      o1[p] = a1 * cv + a2 * sv;
      o2[p] = -a1 * sv + a2 * cv;
      ssq += o1[p] * o1[p] + o2[p] * o2[p];
    }
    ssq += __shfl_xor(ssq, 1);
    ssq += __shfl_xor(ssq, 2);
    ssq += __shfl_xor(ssq, 4);
    float rn = rsqrtf(ssq * (1.f / 64.f) + 1e-6f);
    rn *= (g < 16) ? (1.2f * 0.125f) : 1.2f;
    ushort4 w1, w2;
    w1.x = f2bf(o1[0] * rn); w1.y = f2bf(o1[1] * rn);
    w1.z = f2bf(o1[2] * rn); w1.w = f2bf(o1[3] * rn);
    w2.x = f2bf(o2[0] * rn); w2.y = f2bf(o2[1] * rn);
    w2.z = f2bf(o2[2] * rn); w2.w = f2bf(o2[3] * rn);
    if (g < 16) {
      size_t base = ((size_t)(b * NH + g) * T_SZ + t) * HD;
      *(ushort4*)&qa[base + sub * 4]      = w1;
      *(ushort4*)&qa[base + 32 + sub * 4] = w2;
    } else {
      size_t base = ((size_t)(b * NKV + (g - 16)) * T_SZ + t) * HD;
      *(ushort4*)&ka[base + sub * 4]      = w1;
      *(ushort4*)&ka[base + 32 + sub * 4] = w2;
    }
  }
  {
    int khh = tid >> 6, d = tid & 63;
    float val = row[1280 + tid] + gate[khh] * ve[(size_t)bt * KVD + tid];
    vt[((size_t)(b * NKV + khh) * HD + d) * T_SZ + t] = f2bf(val);
  }
}

// ---------------- causal flash attention, Q-tile=128, no softmax reductions ----------------
// Scores are bounded: |q|=|k|=9.6 after RMSNorm*1.2, s<=9.6^2/8=11.52 -> exp never
// overflows fp32/bf16, so max-subtraction is dropped. Row-sum l is computed by an
// extra MFMA against a ones vector (same C-layout as oacc). Zero cross-lane ops.
#define KSTR 72   // padded LDS row stride (shorts): 144 B, conflict-free b128
__global__ __launch_bounds__(256) void attn(const unsigned short* __restrict__ qa,
                                            const unsigned short* __restrict__ ka,
                                            const unsigned short* __restrict__ vt,
                                            unsigned short* __restrict__ y) {
  int qt = (gridDim.x - 1) - blockIdx.x;   // heavy tiles dispatch first
  int bh = blockIdx.y;
  int b = bh >> 4, h = bh & 15;
  int kh = h >> 2;
  int tid = threadIdx.x;
  int wave = tid >> 6, lane = tid & 63;
  int quad = lane >> 4, l16 = lane & 15;

  __shared__ unsigned short Ks[64 * KSTR];
  __shared__ unsigned short Vs[64 * KSTR];
  __shared__ unsigned short Ps[128 * KSTR];
  unsigned short* Pw = &Ps[(wave * 32) * KSTR];   // this wave's 32 P rows

  // Q: wave owns rows wave*32 .. wave*32+31 (2 m-blocks of 16)
  bf16x8 aq[2][2];
#pragma unroll
  for (int mi = 0; mi < 2; mi++) {
    int tq = qt * 128 + wave * 32 + mi * 16 + l16;
    const unsigned short* qp = &qa[((size_t)(b * NH + h) * T_SZ + tq) * HD];
    aq[mi][0] = *(const bf16x8*)&qp[quad * 8];
    aq[mi][1] = *(const bf16x8*)&qp[32 + quad * 8];
  }

  const unsigned short one_bf = 0x3F80;
  bf16x8 vones = {(short)one_bf, (short)one_bf, (short)one_bf, (short)one_bf,
                  (short)one_bf, (short)one_bf, (short)one_bf, (short)one_bf};

  f32x4 oacc[2][4];
  f32x4 lacc[2];
#pragma unroll
  for (int mi = 0; mi < 2; mi++) {
    lacc[mi] = (f32x4){0.f, 0.f, 0.f, 0.f};
#pragma unroll
    for (int d = 0; d < 4; d++) oacc[mi][d] = (f32x4){0.f, 0.f, 0.f, 0.f};
  }

  int lr = tid >> 2;          // 0..63
  int lc = (tid & 3) * 16;    // 0,16,32,48

  const unsigned short* kbase = &ka[(size_t)(b * NKV + kh) * T_SZ * HD];
  const unsigned short* vbase = &vt[(size_t)(b * NKV + kh) * HD * T_SZ];

  int nj = 2 * qt + 2;   // number of 64-wide K/V tiles

  uint4 k0, k1, v0, v1;
  {
    const unsigned short* kp = &kbase[(size_t)lr * HD + lc];
    const unsigned short* vp = &vbase[(size_t)lr * T_SZ + lc];
    k0 = *(const uint4*)(kp);
    k1 = *(const uint4*)(kp + 8);
    v0 = *(const uint4*)(vp);
    v1 = *(const uint4*)(vp + 8);
  }

  int qrow0 = qt * 128 + wave * 32;

  for (int j = 0; j < nj; j++) {
    __syncthreads();
    *(uint4*)&Ks[lr * KSTR + lc]     = k0;
    *(uint4*)&Ks[lr * KSTR + lc + 8] = k1;
    *(uint4*)&Vs[lr * KSTR + lc]     = v0;
    *(uint4*)&Vs[lr * KSTR + lc + 8] = v1;
    if (j + 1 < nj) {
      const unsigned short* kp = &kbase[(size_t)((j + 1) * 64 + lr) * HD + lc];
      const unsigned short* vp = &vbase[(size_t)lr * T_SZ + (j + 1) * 64 + lc];
      k0 = *(const uint4*)(kp);
      k1 = *(const uint4*)(kp + 8);
      v0 = *(const uint4*)(vp);
      v1 = *(const uint4*)(vp + 8);
    }
    __syncthreads();

    // S = Q K^T (scale pre-folded into q); K-frags shared across both m-blocks
    f32x4 sa[2][4];
#pragma unroll
    for (int nb = 0; nb < 4; nb++) {
      bf16x8 bk0 = *(const bf16x8*)&Ks[(nb * 16 + l16) * KSTR + quad * 8];
      bf16x8 bk1 = *(const bf16x8*)&Ks[(nb * 16 + l16) * KSTR + 32 + quad * 8];
#pragma unroll
      for (int mi = 0; mi < 2; mi++) {
        f32x4 s = (f32x4){0.f, 0.f, 0.f, 0.f};
        s = __builtin_amdgcn_mfma_f32_16x16x32_bf16(aq[mi][0], bk0, s, 0, 0, 0);
        s = __builtin_amdgcn_mfma_f32_16x16x32_bf16(aq[mi][1], bk1, s, 0, 0, 0);
        sa[mi][nb] = s;
      }
    }

    // causal mask (wave-uniform branch; only near-diagonal tiles take it)
#pragma unroll
    for (int mi = 0; mi < 2; mi++) {
      int rowLow = qrow0 + mi * 16;
      if (j * 64 + 63 > rowLow) {
#pragma unroll
        for (int nb = 0; nb < 4; nb++) {
          int col = j * 64 + nb * 16 + l16;
#pragma unroll
          for (int i = 0; i < 4; i++) {
            if (col > rowLow + quad * 4 + i) sa[mi][nb][i] = -__builtin_inff();
          }
        }
      }
    }

    // P = exp(S) straight into LDS (C-layout -> A-layout round trip, same-wave)
#pragma unroll
    for (int mi = 0; mi < 2; mi++)
#pragma unroll
      for (int nb = 0; nb < 4; nb++)
#pragma unroll
        for (int i = 0; i < 4; i++)
          Pw[(mi * 16 + quad * 4 + i) * KSTR + nb * 16 + l16] = f2bf(__expf(sa[mi][nb][i]));

    bf16x8 ap[2][2];
#pragma unroll
    for (int mi = 0; mi < 2; mi++) {
      ap[mi][0] = *(const bf16x8*)&Pw[(mi * 16 + l16) * KSTR + quad * 8];
      ap[mi][1] = *(const bf16x8*)&Pw[(mi * 16 + l16) * KSTR + 32 + quad * 8];
      lacc[mi] = __builtin_amdgcn_mfma_f32_16x16x32_bf16(ap[mi][0], vones, lacc[mi], 0, 0, 0);
      lacc[mi] = __builtin_amdgcn_mfma_f32_16x16x32_bf16(ap[mi][1], vones, lacc[mi], 0, 0, 0);
    }
#pragma unroll
    for (int d = 0; d < 4; d++) {
      bf16x8 bv0 = *(const bf16x8*)&Vs[(d * 16 + l16) * KSTR + quad * 8];
      bf16x8 bv1 = *(const bf16x8*)&Vs[(d * 16 + l16) * KSTR + 32 + quad * 8];
#pragma unroll
      for (int mi = 0; mi < 2; mi++) {
        oacc[mi][d] = __builtin_amdgcn_mfma_f32_16x16x32_bf16(ap[mi][0], bv0, oacc[mi][d], 0, 0, 0);
        oacc[mi][d] = __builtin_amdgcn_mfma_f32_16x16x32_bf16(ap[mi][1], bv1, oacc[mi][d], 0, 0, 0);
      }
    }
  }

  // epilogue
#pragma unroll
  for (int mi = 0; mi < 2; mi++) {
#pragma unroll
    for (int i = 0; i < 4; i++) {
      int tq = qrow0 + mi * 16 + quad * 4 + i;
      float inv = 1.f / lacc[mi][i];
#pragma unroll
      for (int d = 0; d < 4; d++) {
        y[((size_t)(b * T_SZ) + tq) * C_SZ + h * HD + d * 16 + l16] = f2bf(oacc[mi][d][i] * inv);
      }
    }
  }
}

extern "C" void kernel_launch(void* const* d_in, const int* in_sizes, int n_in,
                              void* d_out, int out_size, void* d_ws, size_t ws_size,
                              hipStream_t stream) {
  const float* x    = (const float*)d_in[0];
  const float* ve   = (const float*)d_in[1];
  const float* cosb = (const float*)d_in[2];
  const float* sinb = (const float*)d_in[3];
  const float* Wq   = (const float*)d_in[4];
  const float* Wk   = (const float*)d_in[5];
  const float* Wv   = (const float*)d_in[6];
  const float* Wo   = (const float*)d_in[7];
  const float* Wg   = (const float*)d_in[8];
  float* out = (float*)d_out;

  const size_t MB = 1024 * 1024;
  char* ws = (char*)d_ws;
  unsigned short* xb    = (unsigned short*)(ws);             // 8 MB (reused as yb later)
  unsigned short* wqkvb = (unsigned short*)(ws + 8 * MB);    // 3 MB
  unsigned short* wob   = (unsigned short*)(ws + 11 * MB);   // 2 MB
  float*          qkvf  = (float*)(ws + 13 * MB);            // 24 MB -> ends at 37 MB
  unsigned short* qab   = (unsigned short*)(ws + 37 * MB);   // 8 MB
  unsigned short* kab   = (unsigned short*)(ws + 45 * MB);   // 2 MB
  unsigned short* vtb   = (unsigned short*)(ws + 47 * MB);   // 2 MB -> 49 MB total
  unsigned short* yb    = xb;                                // reuse after gemm1

  auto cvt = [&](const float* s, unsigned short* d, int n) {
    int n4 = n / 4;
    cvt_f32_bf16<<<(n4 + 255) / 256, 256, 0, stream>>>(s, d, n4);
  };
  cvt(x,  xb,                 B_SZ * T_SZ * C_SZ);
  cvt(Wq, wqkvb,              C_SZ * C_SZ);
  cvt(Wk, wqkvb + 1024 * 1024, KVD * C_SZ);
  cvt(Wv, wqkvb + 1280 * 1024, KVD * C_SZ);
  cvt(Wo, wob,                C_SZ * C_SZ);

  gemm_bt<<<dim3(QKV_N / BN, (B_SZ * T_SZ) / BM), 256, 0, stream>>>(
      xb, wqkvb, qkvf, B_SZ * T_SZ, QKV_N, C_SZ);

  postproc<<<B_SZ * T_SZ, 256, 0, stream>>>(qkvf, x, ve, cosb, sinb, Wg, qab, kab, vtb);

  attn<<<dim3(T_SZ / 128, B_SZ * NH), 256, 0, stream>>>(qab, kab, vtb, yb);

  gemm_bt<<<dim3(C_SZ / BN, (B_SZ * T_SZ) / BM), 256, 0, stream>>>(
      yb, wob, out, B_SZ * T_SZ, C_SZ, C_SZ);
}

// Round 4
// 199.154 us; speedup vs baseline: 1.6118x; 1.1771x over previous
//
#include <hip/hip_runtime.h>
#include <stdint.h>

#define B_SZ 2
#define T_SZ 2048
#define C_SZ 1024
#define NH   16
#define NKV  4
#define HD   64
#define KVD  256
#define QKV_N 1536

typedef __attribute__((ext_vector_type(8))) short bf16x8;
typedef __attribute__((ext_vector_type(4))) float f32x4;

#define GL(p) ((const __attribute__((address_space(1))) void*)(p))
#define LD(p) ((__attribute__((address_space(3))) void*)(p))

__device__ inline unsigned short f2bf(float f) {
  union { float f; unsigned u; } v; v.f = f;
  unsigned u = v.u;
  unsigned r = (u + 0x7fffu + ((u >> 16) & 1u)) >> 16;
  return (unsigned short)r;
}
__device__ inline unsigned short bftrunc(float f) {  // truncate: 1 inst; bias cancels in O/l
  union { float f; unsigned u; } v; v.f = f;
  return (unsigned short)(v.u >> 16);
}

// ---------------- fused fp32 -> bf16 convert, 5 segments, 1 launch ----------------
struct Cvt5 {
  const float *s0, *s1, *s2, *s3, *s4;
  unsigned short *d0, *d1, *d2, *d3, *d4;
};
// n4 per segment (compile-time): x 1048576, Wq 262144, Wk 65536, Wv 65536, Wo 262144
// all divisible by 256 -> no bounds checks. total blocks 6656.
__global__ __launch_bounds__(256) void cvt_all(Cvt5 a) {
  int blk = blockIdx.x, tid = threadIdx.x;
  const float* s; unsigned short* d; int i;
  if      (blk < 4096) { s = a.s0; d = a.d0; i = blk * 256 + tid; }
  else if (blk < 5120) { s = a.s1; d = a.d1; i = (blk - 4096) * 256 + tid; }
  else if (blk < 5376) { s = a.s2; d = a.d2; i = (blk - 5120) * 256 + tid; }
  else if (blk < 5632) { s = a.s3; d = a.d3; i = (blk - 5376) * 256 + tid; }
  else                 { s = a.s4; d = a.d4; i = (blk - 5632) * 256 + tid; }
  float4 f = ((const float4*)s)[i];
  ushort4 o;
  o.x = f2bf(f.x); o.y = f2bf(f.y); o.z = f2bf(f.z); o.w = f2bf(f.w);
  ((ushort4*)d)[i] = o;
}

// ---------------- bf16 GEMM:  C[m,n] = sum_k A[m,k]*B[n,k] ----------------
// BM=64 x BN=128: gemm1 grid=768 (exactly 3 blocks/CU), gemm2 grid=512 (2/CU), balanced.
#define BM 64
#define BN 128
#define BK 32
__global__ __launch_bounds__(256) void gemm_bt(const unsigned short* __restrict__ A,
                                               const unsigned short* __restrict__ Bm,
                                               float* __restrict__ C,
                                               int M, int N, int K) {
  __shared__ unsigned short As[BM * BK];   // unpadded: required by global_load_lds
  __shared__ unsigned short Bs[BN * BK];
  int tid  = threadIdx.x;
  int lane = tid & 63;
  int wave = tid >> 6;
  int quad = lane >> 4;
  int l16  = lane & 15;
  int m0 = blockIdx.y * BM;
  int n0 = blockIdx.x * BN;
  int wm = (wave & 1) * 32;
  int wn = (wave >> 1) * 64;

  f32x4 acc[2][4];
#pragma unroll
  for (int i = 0; i < 2; i++)
#pragma unroll
    for (int j = 0; j < 4; j++) acc[i][j] = (f32x4){0.f, 0.f, 0.f, 0.f};

  // staging: wave w owns A rows w*16..+15, B rows w*16..+15 and 64+w*16..+15
  int srow = wave * 16;
  int lrow = lane >> 2;
  int lcol = (lane & 3) * 8;
  const unsigned short* aP  = &A[(size_t)(m0 + srow + lrow) * K + lcol];
  const unsigned short* b0P = &Bm[(size_t)(n0 + srow + lrow) * K + lcol];
  const unsigned short* b1P = b0P + 64 * (size_t)K;
  unsigned short* lA  = &As[srow * BK];
  unsigned short* lB0 = &Bs[srow * BK];
  unsigned short* lB1 = &Bs[(64 + srow) * BK];

  for (int k0 = 0; k0 < K; k0 += BK) {
    __syncthreads();
    __builtin_amdgcn_global_load_lds(GL(aP + k0),  LD(lA),  16, 0, 0);
    __builtin_amdgcn_global_load_lds(GL(b0P + k0), LD(lB0), 16, 0, 0);
    __builtin_amdgcn_global_load_lds(GL(b1P + k0), LD(lB1), 16, 0, 0);
    __syncthreads();

    bf16x8 af[2], bfr[4];
#pragma unroll
    for (int i = 0; i < 2; i++)
      af[i] = *(const bf16x8*)&As[(wm + i * 16 + l16) * BK + quad * 8];
#pragma unroll
    for (int j = 0; j < 4; j++)
      bfr[j] = *(const bf16x8*)&Bs[(wn + j * 16 + l16) * BK + quad * 8];
#pragma unroll
    for (int i = 0; i < 2; i++)
#pragma unroll
      for (int j = 0; j < 4; j++)
        acc[i][j] = __builtin_amdgcn_mfma_f32_16x16x32_bf16(af[i], bfr[j], acc[i][j], 0, 0, 0);
  }

#pragma unroll
  for (int i = 0; i < 2; i++) {
#pragma unroll
    for (int j = 0; j < 4; j++) {
      int col = n0 + wn + j * 16 + l16;
#pragma unroll
      for (int r = 0; r < 4; r++) {
        int row = m0 + wm + i * 16 + quad * 4 + r;
        C[(size_t)row * N + col] = acc[i][j][r];
      }
    }
  }
}

// ---------------- gate+ve, RoPE, RMSNorm, layout for attention ----------------
// q scale folds 1.2 * (1/8) * log2(e) so attention can use exp2 directly.
__global__ __launch_bounds__(256) void postproc(const float* __restrict__ qkv,
                                                const float* __restrict__ x,
                                                const float* __restrict__ ve,
                                                const float* __restrict__ cosb,
                                                const float* __restrict__ sinb,
                                                const float* __restrict__ Wg,
                                                unsigned short* __restrict__ qa,
                                                unsigned short* __restrict__ ka,
                                                unsigned short* __restrict__ vt) {
  int bt = blockIdx.x;
  int b = bt >> 11;
  int t = bt & 2047;
  int tid = threadIdx.x;
  __shared__ float row[QKV_N];
  __shared__ float gate[4];
  for (int i = tid; i < QKV_N; i += 256) row[i] = qkv[(size_t)bt * QKV_N + i];
  if (tid < 4) {
    float s = 0.f;
#pragma unroll
    for (int j = 0; j < 12; j++) s += x[(size_t)bt * C_SZ + j] * Wg[tid * 12 + j];
    gate[tid] = 3.f / (1.f + __expf(-s));
  }
  __syncthreads();

  int g = tid >> 3, sub = tid & 7;
  if (g < 20) {
    int off = (g < 16) ? g * 64 : 1024 + (g - 16) * 64;
    float o1[4], o2[4];
    float ssq = 0.f;
#pragma unroll
    for (int p = 0; p < 4; p++) {
      int j = sub * 4 + p;
      float cv = cosb[t * 32 + j];
      float sv = sinb[t * 32 + j];
      float a1 = row[off + j];
      float a2 = row[off + 32 + j];
      o1[p] = a1 * cv + a2 * sv;
      o2[p] = -a1 * sv + a2 * cv;
      ssq += o1[p] * o1[p] + o2[p] * o2[p];
    }
    ssq += __shfl_xor(ssq, 1);
    ssq += __shfl_xor(ssq, 2);
    ssq += __shfl_xor(ssq, 4);
    float rn = rsqrtf(ssq * (1.f / 64.f) + 1e-6f);
    rn *= (g < 16) ? (0.15f * 1.44269504088896f) : 1.2f;  // q: 1.2/8*log2e ; k: 1.2
    ushort4 w1, w2;
    w1.x = f2bf(o1[0] * rn); w1.y = f2bf(o1[1] * rn);
    w1.z = f2bf(o1[2] * rn); w1.w = f2bf(o1[3] * rn);
    w2.x = f2bf(o2[0] * rn); w2.y = f2bf(o2[1] * rn);
    w2.z = f2bf(o2[2] * rn); w2.w = f2bf(o2[3] * rn);
    if (g < 16) {
      size_t base = ((size_t)(b * NH + g) * T_SZ + t) * HD;
      *(ushort4*)&qa[base + sub * 4]      = w1;
      *(ushort4*)&qa[base + 32 + sub * 4] = w2;
    } else {
      size_t base = ((size_t)(b * NKV + (g - 16)) * T_SZ + t) * HD;
      *(ushort4*)&ka[base + sub * 4]      = w1;
      *(ushort4*)&ka[base + 32 + sub * 4] = w2;
    }
  }
  {
    int khh = tid >> 6, d = tid & 63;
    float val = row[1280 + tid] + gate[khh] * ve[(size_t)bt * KVD + tid];
    vt[((size_t)(b * NKV + khh) * HD + d) * T_SZ + t] = f2bf(val);
  }
}

// ---------------- causal flash attention, Q-tile=128, exp2 softmax, no reductions ----------------
// |q|=|k| fixed by RMSNorm -> scores bounded (<=11.52 nats) -> no max-subtraction.
// P = exp2(S) (log2e folded into q). Row-sum l via ones-MFMA. P stored truncated bf16
// (downward bias cancels exactly in O/l since l uses the same bf16 P).
#define KSTR 72   // padded LDS row stride (shorts): 144 B, conflict-free b128
__global__ __launch_bounds__(256) void attn(const unsigned short* __restrict__ qa,
                                            const unsigned short* __restrict__ ka,
                                            const unsigned short* __restrict__ vt,
                                            unsigned short* __restrict__ y) {
  // 1D grid, 512 blocks: pair qt with 15-qt so co-resident blocks sum to equal work
  int bid = blockIdx.x;
  int half = bid >> 8, r = bid & 255;
  int qt = half ? (r & 15) : 15 - (r & 15);
  int bh = (half << 4) | (r >> 4);
  int b = bh >> 4, h = bh & 15;
  int kh = h >> 2;
  int tid = threadIdx.x;
  int wave = tid >> 6, lane = tid & 63;
  int quad = lane >> 4, l16 = lane & 15;

  __shared__ unsigned short Ks[64 * KSTR];
  __shared__ unsigned short Vs[64 * KSTR];
  __shared__ unsigned short Ps[128 * KSTR];
  unsigned short* Pw = &Ps[(wave * 32) * KSTR];   // this wave's 32 P rows

  bf16x8 aq[2][2];
#pragma unroll
  for (int mi = 0; mi < 2; mi++) {
    int tq = qt * 128 + wave * 32 + mi * 16 + l16;
    const unsigned short* qp = &qa[((size_t)(b * NH + h) * T_SZ + tq) * HD];
    aq[mi][0] = *(const bf16x8*)&qp[quad * 8];
    aq[mi][1] = *(const bf16x8*)&qp[32 + quad * 8];
  }

  const unsigned short one_bf = 0x3F80;
  bf16x8 vones = {(short)one_bf, (short)one_bf, (short)one_bf, (short)one_bf,
                  (short)one_bf, (short)one_bf, (short)one_bf, (short)one_bf};

  f32x4 oacc[2][4];
  f32x4 lacc[2];
#pragma unroll
  for (int mi = 0; mi < 2; mi++) {
    lacc[mi] = (f32x4){0.f, 0.f, 0.f, 0.f};
#pragma unroll
    for (int d = 0; d < 4; d++) oacc[mi][d] = (f32x4){0.f, 0.f, 0.f, 0.f};
  }

  int lr = tid >> 2;          // 0..63
  int lc = (tid & 3) * 16;    // 0,16,32,48

  const unsigned short* kbase = &ka[(size_t)(b * NKV + kh) * T_SZ * HD];
  const unsigned short* vbase = &vt[(size_t)(b * NKV + kh) * HD * T_SZ];

  int nj = 2 * qt + 2;   // number of 64-wide K/V tiles

  uint4 k0, k1, v0, v1;
  {
    const unsigned short* kp = &kbase[(size_t)lr * HD + lc];
    const unsigned short* vp = &vbase[(size_t)lr * T_SZ + lc];
    k0 = *(const uint4*)(kp);
    k1 = *(const uint4*)(kp + 8);
    v0 = *(const uint4*)(vp);
    v1 = *(const uint4*)(vp + 8);
  }

  int qrow0 = qt * 128 + wave * 32;

  for (int j = 0; j < nj; j++) {
    __syncthreads();
    *(uint4*)&Ks[lr * KSTR + lc]     = k0;
    *(uint4*)&Ks[lr * KSTR + lc + 8] = k1;
    *(uint4*)&Vs[lr * KSTR + lc]     = v0;
    *(uint4*)&Vs[lr * KSTR + lc + 8] = v1;
    if (j + 1 < nj) {
      const unsigned short* kp = &kbase[(size_t)((j + 1) * 64 + lr) * HD + lc];
      const unsigned short* vp = &vbase[(size_t)lr * T_SZ + (j + 1) * 64 + lc];
      k0 = *(const uint4*)(kp);
      k1 = *(const uint4*)(kp + 8);
      v0 = *(const uint4*)(vp);
      v1 = *(const uint4*)(vp + 8);
    }
    __syncthreads();

    // S' = Q K^T (scale*log2e pre-folded into q); K-frags shared across both m-blocks
    f32x4 sa[2][4];
#pragma unroll
    for (int nb = 0; nb < 4; nb++) {
      bf16x8 bk0 = *(const bf16x8*)&Ks[(nb * 16 + l16) * KSTR + quad * 8];
      bf16x8 bk1 = *(const bf16x8*)&Ks[(nb * 16 + l16) * KSTR + 32 + quad * 8];
#pragma unroll
      for (int mi = 0; mi < 2; mi++) {
        f32x4 s = (f32x4){0.f, 0.f, 0.f, 0.f};
        s = __builtin_amdgcn_mfma_f32_16x16x32_bf16(aq[mi][0], bk0, s, 0, 0, 0);
        s = __builtin_amdgcn_mfma_f32_16x16x32_bf16(aq[mi][1], bk1, s, 0, 0, 0);
        sa[mi][nb] = s;
      }
    }

    // causal mask (wave-uniform branch; only near-diagonal tiles take it)
#pragma unroll
    for (int mi = 0; mi < 2; mi++) {
      int rowLow = qrow0 + mi * 16;
      if (j * 64 + 63 > rowLow) {
#pragma unroll
        for (int nb = 0; nb < 4; nb++) {
          int col = j * 64 + nb * 16 + l16;
#pragma unroll
          for (int i = 0; i < 4; i++) {
            if (col > rowLow + quad * 4 + i) sa[mi][nb][i] = -__builtin_inff();
          }
        }
      }
    }

    // P = exp2(S') -> truncated bf16 -> LDS (C-layout -> A-layout, same-wave region)
#pragma unroll
    for (int mi = 0; mi < 2; mi++)
#pragma unroll
      for (int nb = 0; nb < 4; nb++)
#pragma unroll
        for (int i = 0; i < 4; i++)
          Pw[(mi * 16 + quad * 4 + i) * KSTR + nb * 16 + l16] =
              bftrunc(__builtin_amdgcn_exp2f(sa[mi][nb][i]));

    bf16x8 ap[2][2];
#pragma unroll
    for (int mi = 0; mi < 2; mi++) {
      ap[mi][0] = *(const bf16x8*)&Pw[(mi * 16 + l16) * KSTR + quad * 8];
      ap[mi][1] = *(const bf16x8*)&Pw[(mi * 16 + l16) * KSTR + 32 + quad * 8];
      lacc[mi] = __builtin_amdgcn_mfma_f32_16x16x32_bf16(ap[mi][0], vones, lacc[mi], 0, 0, 0);
      lacc[mi] = __builtin_amdgcn_mfma_f32_16x16x32_bf16(ap[mi][1], vones, lacc[mi], 0, 0, 0);
    }
#pragma unroll
    for (int d = 0; d < 4; d++) {
      bf16x8 bv0 = *(const bf16x8*)&Vs[(d * 16 + l16) * KSTR + quad * 8];
      bf16x8 bv1 = *(const bf16x8*)&Vs[(d * 16 + l16) * KSTR + 32 + quad * 8];
#pragma unroll
      for (int mi = 0; mi < 2; mi++) {
        oacc[mi][d] = __builtin_amdgcn_mfma_f32_16x16x32_bf16(ap[mi][0], bv0, oacc[mi][d], 0, 0, 0);
        oacc[mi][d] = __builtin_amdgcn_mfma_f32_16x16x32_bf16(ap[mi][1], bv1, oacc[mi][d], 0, 0, 0);
      }
    }
  }

  // epilogue
#pragma unroll
  for (int mi = 0; mi < 2; mi++) {
#pragma unroll
    for (int i = 0; i < 4; i++) {
      int tq = qrow0 + mi * 16 + quad * 4 + i;
      float inv = 1.f / lacc[mi][i];
#pragma unroll
      for (int d = 0; d < 4; d++) {
        y[((size_t)(b * T_SZ) + tq) * C_SZ + h * HD + d * 16 + l16] = f2bf(oacc[mi][d][i] * inv);
      }
    }
  }
}

extern "C" void kernel_launch(void* const* d_in, const int* in_sizes, int n_in,
                              void* d_out, int out_size, void* d_ws, size_t ws_size,
                              hipStream_t stream) {
  const float* x    = (const float*)d_in[0];
  const float* ve   = (const float*)d_in[1];
  const float* cosb = (const float*)d_in[2];
  const float* sinb = (const float*)d_in[3];
  const float* Wq   = (const float*)d_in[4];
  const float* Wk   = (const float*)d_in[5];
  const float* Wv   = (const float*)d_in[6];
  const float* Wo   = (const float*)d_in[7];
  const float* Wg   = (const float*)d_in[8];
  float* out = (float*)d_out;

  const size_t MB = 1024 * 1024;
  char* ws = (char*)d_ws;
  unsigned short* xb    = (unsigned short*)(ws);             // 8 MB (reused as yb later)
  unsigned short* wqkvb = (unsigned short*)(ws + 8 * MB);    // 3 MB
  unsigned short* wob   = (unsigned short*)(ws + 11 * MB);   // 2 MB
  float*          qkvf  = (float*)(ws + 13 * MB);            // 24 MB -> ends at 37 MB
  unsigned short* qab   = (unsigned short*)(ws + 37 * MB);   // 8 MB
  unsigned short* kab   = (unsigned short*)(ws + 45 * MB);   // 2 MB
  unsigned short* vtb   = (unsigned short*)(ws + 47 * MB);   // 2 MB -> 49 MB total
  unsigned short* yb    = xb;                                // reuse after gemm1

  Cvt5 ca;
  ca.s0 = x;  ca.d0 = xb;
  ca.s1 = Wq; ca.d1 = wqkvb;
  ca.s2 = Wk; ca.d2 = wqkvb + 1024 * 1024;
  ca.s3 = Wv; ca.d3 = wqkvb + 1280 * 1024;
  ca.s4 = Wo; ca.d4 = wob;
  cvt_all<<<6656, 256, 0, stream>>>(ca);

  gemm_bt<<<dim3(QKV_N / BN, (B_SZ * T_SZ) / BM), 256, 0, stream>>>(
      xb, wqkvb, qkvf, B_SZ * T_SZ, QKV_N, C_SZ);

  postproc<<<B_SZ * T_SZ, 256, 0, stream>>>(qkvf, x, ve, cosb, sinb, Wg, qab, kab, vtb);

  attn<<<512, 256, 0, stream>>>(qab, kab, vtb, yb);

  gemm_bt<<<dim3(C_SZ / BN, (B_SZ * T_SZ) / BM), 256, 0, stream>>>(
      yb, wob, out, B_SZ * T_SZ, C_SZ, C_SZ);
}

// Round 5
// 179.772 us; speedup vs baseline: 1.7855x; 1.1078x over previous
//
#include <hip/hip_runtime.h>
#include <stdint.h>

#define B_SZ 2
#define T_SZ 2048
#define C_SZ 1024
#define NH   16
#define NKV  4
#define HD   64
#define KVD  256
#define QKV_N 1536

typedef __attribute__((ext_vector_type(8))) short bf16x8;
typedef __attribute__((ext_vector_type(4))) float f32x4;

#define GL(p) ((const __attribute__((address_space(1))) void*)(p))
#define LD(p) ((__attribute__((address_space(3))) void*)(p))

__device__ inline unsigned short f2bf(float f) {
  union { float f; unsigned u; } v; v.f = f;
  unsigned u = v.u;
  unsigned r = (u + 0x7fffu + ((u >> 16) & 1u)) >> 16;
  return (unsigned short)r;
}
__device__ inline unsigned short bftrunc(float f) {  // truncate: 1 inst; bias cancels in O/l
  union { float f; unsigned u; } v; v.f = f;
  return (unsigned short)(v.u >> 16);
}

// ---------------- fused fp32->bf16 convert (5 segments) + gate precompute, 1 launch ----------------
struct CvtArgs {
  const float *s0, *s1, *s2, *s3, *s4;
  unsigned short *d0, *d1, *d2, *d3, *d4;
  const float *x, *Wg;
  float *gate;           // [B*T][NKV]
};
// segs (n4/256 blocks): x 4096, Wq 1024, Wk 256, Wv 256, Wo 1024 -> 6656; gate: 64 -> 6720 total
__global__ __launch_bounds__(256) void cvt_all(CvtArgs a) {
  int blk = blockIdx.x, tid = threadIdx.x;
  if (blk >= 6656) {  // gate: 3*sigmoid(x[:, :12] @ Wg^T), one value per thread
    int idx = (blk - 6656) * 256 + tid;      // 0..16383
    int bt = idx >> 2, kh = idx & 3;
    float s = 0.f;
#pragma unroll
    for (int j = 0; j < 12; j++) s += a.x[(size_t)bt * C_SZ + j] * a.Wg[kh * 12 + j];
    a.gate[idx] = 3.f / (1.f + __expf(-s));
    return;
  }
  const float* s; unsigned short* d; int i;
  if      (blk < 4096) { s = a.s0; d = a.d0; i = blk * 256 + tid; }
  else if (blk < 5120) { s = a.s1; d = a.d1; i = (blk - 4096) * 256 + tid; }
  else if (blk < 5376) { s = a.s2; d = a.d2; i = (blk - 5120) * 256 + tid; }
  else if (blk < 5632) { s = a.s3; d = a.d3; i = (blk - 5376) * 256 + tid; }
  else                 { s = a.s4; d = a.d4; i = (blk - 5632) * 256 + tid; }
  float4 f = ((const float4*)s)[i];
  ushort4 o;
  o.x = f2bf(f.x); o.y = f2bf(f.y); o.z = f2bf(f.z); o.w = f2bf(f.w);
  ((ushort4*)d)[i] = o;
}

// ================= shared GEMM core: BM=64 x BN=128, BK=64 as two BK=32 panels =================
#define BM 64
#define BN 128
#define GEMM_PROLOG(A, Bm, K)                                                        \
  __shared__ unsigned short As[2][BM * 32];                                          \
  __shared__ unsigned short Bs[2][BN * 32];                                          \
  int tid  = threadIdx.x;                                                            \
  int lane = tid & 63;                                                               \
  int wave = tid >> 6;                                                               \
  int quad = lane >> 4;                                                              \
  int l16  = lane & 15;                                                              \
  int m0 = blockIdx.y * BM;                                                          \
  int n0 = blockIdx.x * BN;                                                          \
  int wm = (wave & 1) * 32;                                                          \
  int wn = (wave >> 1) * 64;                                                         \
  f32x4 acc[2][4];                                                                   \
  _Pragma("unroll") for (int i = 0; i < 2; i++)                                      \
    _Pragma("unroll") for (int j = 0; j < 4; j++)                                    \
      acc[i][j] = (f32x4){0.f, 0.f, 0.f, 0.f};                                       \
  int lrow = lane >> 2;                                                              \
  int lcol = (lane & 3) * 8;                                                         \
  int srowA = wave * 16;                                                             \
  int srowB = wave * 32;                                                             \
  const unsigned short* aP  = &A[(size_t)(m0 + srowA + lrow) * K + lcol];            \
  const unsigned short* b0P = &Bm[(size_t)(n0 + srowB + lrow) * K + lcol];           \
  const unsigned short* b1P = b0P + 16 * (size_t)K;                                  \
  for (int k0 = 0; k0 < K; k0 += 64) {                                               \
    __syncthreads();                                                                 \
    _Pragma("unroll") for (int p = 0; p < 2; p++) {                                  \
      __builtin_amdgcn_global_load_lds(GL(aP  + k0 + p * 32), LD(&As[p][srowA * 32]), 16, 0, 0); \
      __builtin_amdgcn_global_load_lds(GL(b0P + k0 + p * 32), LD(&Bs[p][srowB * 32]), 16, 0, 0); \
      __builtin_amdgcn_global_load_lds(GL(b1P + k0 + p * 32), LD(&Bs[p][(srowB + 16) * 32]), 16, 0, 0); \
    }                                                                                \
    __syncthreads();                                                                 \
    _Pragma("unroll") for (int p = 0; p < 2; p++) {                                  \
      bf16x8 af[2], bfr[4];                                                          \
      _Pragma("unroll") for (int i = 0; i < 2; i++)                                  \
        af[i] = *(const bf16x8*)&As[p][(wm + i * 16 + l16) * 32 + quad * 8];         \
      _Pragma("unroll") for (int j = 0; j < 4; j++)                                  \
        bfr[j] = *(const bf16x8*)&Bs[p][(wn + j * 16 + l16) * 32 + quad * 8];        \
      _Pragma("unroll") for (int i = 0; i < 2; i++)                                  \
        _Pragma("unroll") for (int j = 0; j < 4; j++)                                \
          acc[i][j] = __builtin_amdgcn_mfma_f32_16x16x32_bf16(af[i], bfr[j], acc[i][j], 0, 0, 0); \
    }                                                                                \
  }

// ---------------- gemm2: C[m,n] = sum_k A[m,k]*B[n,k], fp32 out ----------------
__global__ __launch_bounds__(256) void gemm_bt(const unsigned short* __restrict__ A,
                                               const unsigned short* __restrict__ Bm,
                                               float* __restrict__ C,
                                               int N, int K) {
  GEMM_PROLOG(A, Bm, K)
#pragma unroll
  for (int i = 0; i < 2; i++) {
#pragma unroll
    for (int j = 0; j < 4; j++) {
      int col = n0 + wn + j * 16 + l16;
#pragma unroll
      for (int r = 0; r < 4; r++) {
        int row = m0 + wm + i * 16 + quad * 4 + r;
        C[(size_t)row * N + col] = acc[i][j][r];
      }
    }
  }
}

// ---------------- gemm1 fused: qkv proj + RoPE + RMSNorm + gate*ve, bf16 out ----------------
// Wave's 64 cols = exactly one head. RoPE partners are acc[i][j] / acc[i][j+2] (same lane).
// q scale folds 1.2 * (1/8) * log2(e) so attention uses exp2. k scale 1.2.
// vt written transposed (B,NKV,HD,T) for the PV B-operand.
__global__ __launch_bounds__(256) void gemm_qkv(const unsigned short* __restrict__ A,
                                                const unsigned short* __restrict__ Bm,
                                                const float* __restrict__ ve,
                                                const float* __restrict__ cosb,
                                                const float* __restrict__ sinb,
                                                const float* __restrict__ gateArr,
                                                unsigned short* __restrict__ qa,
                                                unsigned short* __restrict__ ka,
                                                unsigned short* __restrict__ vt) {
  const int K = C_SZ;
  GEMM_PROLOG(A, Bm, K)

  int colbase = n0 + wn;   // multiple of 64
  if (colbase < 1280) {    // Q or K head
    int isQ = colbase < 1024;
    int h   = isQ ? (colbase >> 6) : ((colbase - 1024) >> 6);
    float scale = isQ ? (0.15f * 1.44269504088896f) : 1.2f;
    unsigned short* dst = isQ ? qa : ka;
    int nheads = isQ ? NH : NKV;
#pragma unroll
    for (int i = 0; i < 2; i++) {
#pragma unroll
      for (int r = 0; r < 4; r++) {
        int row = m0 + wm + i * 16 + quad * 4 + r;   // bt
        int t = row & (T_SZ - 1), b = row >> 11;
        float a10 = acc[i][0][r], a11 = acc[i][1][r];
        float a20 = acc[i][2][r], a21 = acc[i][3][r];
        float cv0 = cosb[t * 32 + l16],      sv0 = sinb[t * 32 + l16];
        float cv1 = cosb[t * 32 + 16 + l16], sv1 = sinb[t * 32 + 16 + l16];
        float o10 =  a10 * cv0 + a20 * sv0;
        float o11 =  a11 * cv1 + a21 * sv1;
        float o20 = -a10 * sv0 + a20 * cv0;
        float o21 = -a11 * sv1 + a21 * cv1;
        float ssq = o10 * o10 + o11 * o11 + o20 * o20 + o21 * o21;
        ssq += __shfl_xor(ssq, 1);
        ssq += __shfl_xor(ssq, 2);
        ssq += __shfl_xor(ssq, 4);
        ssq += __shfl_xor(ssq, 8);
        float rn = rsqrtf(ssq * (1.f / 64.f) + 1e-6f) * scale;
        size_t base = ((size_t)(b * nheads + h) * T_SZ + t) * HD;
        dst[base + l16]      = f2bf(o10 * rn);
        dst[base + 16 + l16] = f2bf(o11 * rn);
        dst[base + 32 + l16] = f2bf(o20 * rn);
        dst[base + 48 + l16] = f2bf(o21 * rn);
      }
    }
  } else {                 // V head: add gate*ve, write transposed
    int kh = (colbase - 1280) >> 6;
#pragma unroll
    for (int i = 0; i < 2; i++) {
#pragma unroll
      for (int r = 0; r < 4; r++) {
        int row = m0 + wm + i * 16 + quad * 4 + r;   // bt
        int t = row & (T_SZ - 1), b = row >> 11;
        float g = gateArr[row * 4 + kh];
        size_t vbase = ((size_t)(b * NKV + kh) * HD) * T_SZ;
#pragma unroll
        for (int j = 0; j < 4; j++) {
          int d = j * 16 + l16;
          float val = acc[i][j][r] + g * ve[(size_t)row * KVD + kh * HD + d];
          vt[vbase + (size_t)d * T_SZ + t] = f2bf(val);
        }
      }
    }
  }
}

// ---------------- causal flash attention, Q-tile=128, exp2 softmax, no reductions ----------------
#define KSTR 72   // padded LDS row stride (shorts): 144 B, conflict-free b128
__global__ __launch_bounds__(256) void attn(const unsigned short* __restrict__ qa,
                                            const unsigned short* __restrict__ ka,
                                            const unsigned short* __restrict__ vt,
                                            unsigned short* __restrict__ y) {
  // 1D grid, 512 blocks: pair qt with 15-qt so co-resident blocks sum to equal work
  int bid = blockIdx.x;
  int half = bid >> 8, r = bid & 255;
  int qt = half ? (r & 15) : 15 - (r & 15);
  int bh = (half << 4) | (r >> 4);
  int b = bh >> 4, h = bh & 15;
  int kh = h >> 2;
  int tid = threadIdx.x;
  int wave = tid >> 6, lane = tid & 63;
  int quad = lane >> 4, l16 = lane & 15;

  __shared__ unsigned short Ks[64 * KSTR];
  __shared__ unsigned short Vs[64 * KSTR];
  __shared__ unsigned short Ps[128 * KSTR];
  unsigned short* Pw = &Ps[(wave * 32) * KSTR];

  bf16x8 aq[2][2];
#pragma unroll
  for (int mi = 0; mi < 2; mi++) {
    int tq = qt * 128 + wave * 32 + mi * 16 + l16;
    const unsigned short* qp = &qa[((size_t)(b * NH + h) * T_SZ + tq) * HD];
    aq[mi][0] = *(const bf16x8*)&qp[quad * 8];
    aq[mi][1] = *(const bf16x8*)&qp[32 + quad * 8];
  }

  const unsigned short one_bf = 0x3F80;
  bf16x8 vones = {(short)one_bf, (short)one_bf, (short)one_bf, (short)one_bf,
                  (short)one_bf, (short)one_bf, (short)one_bf, (short)one_bf};

  f32x4 oacc[2][4];
  f32x4 lacc[2];
#pragma unroll
  for (int mi = 0; mi < 2; mi++) {
    lacc[mi] = (f32x4){0.f, 0.f, 0.f, 0.f};
#pragma unroll
    for (int d = 0; d < 4; d++) oacc[mi][d] = (f32x4){0.f, 0.f, 0.f, 0.f};
  }

  int lr = tid >> 2;          // 0..63
  int lc = (tid & 3) * 16;    // 0,16,32,48

  const unsigned short* kbase = &ka[(size_t)(b * NKV + kh) * T_SZ * HD];
  const unsigned short* vbase = &vt[(size_t)(b * NKV + kh) * HD * T_SZ];

  int nj = 2 * qt + 2;

  uint4 k0, k1, v0, v1;
  {
    const unsigned short* kp = &kbase[(size_t)lr * HD + lc];
    const unsigned short* vp = &vbase[(size_t)lr * T_SZ + lc];
    k0 = *(const uint4*)(kp);
    k1 = *(const uint4*)(kp + 8);
    v0 = *(const uint4*)(vp);
    v1 = *(const uint4*)(vp + 8);
  }

  int qrow0 = qt * 128 + wave * 32;

  for (int j = 0; j < nj; j++) {
    __syncthreads();
    *(uint4*)&Ks[lr * KSTR + lc]     = k0;
    *(uint4*)&Ks[lr * KSTR + lc + 8] = k1;
    *(uint4*)&Vs[lr * KSTR + lc]     = v0;
    *(uint4*)&Vs[lr * KSTR + lc + 8] = v1;
    if (j + 1 < nj) {
      const unsigned short* kp = &kbase[(size_t)((j + 1) * 64 + lr) * HD + lc];
      const unsigned short* vp = &vbase[(size_t)lr * T_SZ + (j + 1) * 64 + lc];
      k0 = *(const uint4*)(kp);
      k1 = *(const uint4*)(kp + 8);
      v0 = *(const uint4*)(vp);
      v1 = *(const uint4*)(vp + 8);
    }
    __syncthreads();

    f32x4 sa[2][4];
#pragma unroll
    for (int nb = 0; nb < 4; nb++) {
      bf16x8 bk0 = *(const bf16x8*)&Ks[(nb * 16 + l16) * KSTR + quad * 8];
      bf16x8 bk1 = *(const bf16x8*)&Ks[(nb * 16 + l16) * KSTR + 32 + quad * 8];
#pragma unroll
      for (int mi = 0; mi < 2; mi++) {
        f32x4 s = (f32x4){0.f, 0.f, 0.f, 0.f};
        s = __builtin_amdgcn_mfma_f32_16x16x32_bf16(aq[mi][0], bk0, s, 0, 0, 0);
        s = __builtin_amdgcn_mfma_f32_16x16x32_bf16(aq[mi][1], bk1, s, 0, 0, 0);
        sa[mi][nb] = s;
      }
    }

#pragma unroll
    for (int mi = 0; mi < 2; mi++) {
      int rowLow = qrow0 + mi * 16;
      if (j * 64 + 63 > rowLow) {
#pragma unroll
        for (int nb = 0; nb < 4; nb++) {
          int col = j * 64 + nb * 16 + l16;
#pragma unroll
          for (int i = 0; i < 4; i++) {
            if (col > rowLow + quad * 4 + i) sa[mi][nb][i] = -__builtin_inff();
          }
        }
      }
    }

#pragma unroll
    for (int mi = 0; mi < 2; mi++)
#pragma unroll
      for (int nb = 0; nb < 4; nb++)
#pragma unroll
        for (int i = 0; i < 4; i++)
          Pw[(mi * 16 + quad * 4 + i) * KSTR + nb * 16 + l16] =
              bftrunc(__builtin_amdgcn_exp2f(sa[mi][nb][i]));

    bf16x8 ap[2][2];
#pragma unroll
    for (int mi = 0; mi < 2; mi++) {
      ap[mi][0] = *(const bf16x8*)&Pw[(mi * 16 + l16) * KSTR + quad * 8];
      ap[mi][1] = *(const bf16x8*)&Pw[(mi * 16 + l16) * KSTR + 32 + quad * 8];
      lacc[mi] = __builtin_amdgcn_mfma_f32_16x16x32_bf16(ap[mi][0], vones, lacc[mi], 0, 0, 0);
      lacc[mi] = __builtin_amdgcn_mfma_f32_16x16x32_bf16(ap[mi][1], vones, lacc[mi], 0, 0, 0);
    }
#pragma unroll
    for (int d = 0; d < 4; d++) {
      bf16x8 bv0 = *(const bf16x8*)&Vs[(d * 16 + l16) * KSTR + quad * 8];
      bf16x8 bv1 = *(const bf16x8*)&Vs[(d * 16 + l16) * KSTR + 32 + quad * 8];
#pragma unroll
      for (int mi = 0; mi < 2; mi++) {
        oacc[mi][d] = __builtin_amdgcn_mfma_f32_16x16x32_bf16(ap[mi][0], bv0, oacc[mi][d], 0, 0, 0);
        oacc[mi][d] = __builtin_amdgcn_mfma_f32_16x16x32_bf16(ap[mi][1], bv1, oacc[mi][d], 0, 0, 0);
      }
    }
  }

#pragma unroll
  for (int mi = 0; mi < 2; mi++) {
#pragma unroll
    for (int i = 0; i < 4; i++) {
      int tq = qrow0 + mi * 16 + quad * 4 + i;
      float inv = 1.f / lacc[mi][i];
#pragma unroll
      for (int d = 0; d < 4; d++) {
        y[((size_t)(b * T_SZ) + tq) * C_SZ + h * HD + d * 16 + l16] = f2bf(oacc[mi][d][i] * inv);
      }
    }
  }
}

extern "C" void kernel_launch(void* const* d_in, const int* in_sizes, int n_in,
                              void* d_out, int out_size, void* d_ws, size_t ws_size,
                              hipStream_t stream) {
  const float* x    = (const float*)d_in[0];
  const float* ve   = (const float*)d_in[1];
  const float* cosb = (const float*)d_in[2];
  const float* sinb = (const float*)d_in[3];
  const float* Wq   = (const float*)d_in[4];
  const float* Wk   = (const float*)d_in[5];
  const float* Wv   = (const float*)d_in[6];
  const float* Wo   = (const float*)d_in[7];
  const float* Wg   = (const float*)d_in[8];
  float* out = (float*)d_out;

  const size_t MB = 1024 * 1024;
  char* ws = (char*)d_ws;
  unsigned short* xb    = (unsigned short*)(ws);             // 8 MB (reused as yb)
  unsigned short* wqkvb = (unsigned short*)(ws + 8 * MB);    // 3 MB
  unsigned short* wob   = (unsigned short*)(ws + 11 * MB);   // 2 MB
  unsigned short* qab   = (unsigned short*)(ws + 13 * MB);   // 8 MB
  unsigned short* kab   = (unsigned short*)(ws + 21 * MB);   // 2 MB
  unsigned short* vtb   = (unsigned short*)(ws + 23 * MB);   // 2 MB
  float*          gateA = (float*)(ws + 25 * MB);            // 64 KB
  unsigned short* yb    = xb;                                // reuse after gemm_qkv

  CvtArgs ca;
  ca.s0 = x;  ca.d0 = xb;
  ca.s1 = Wq; ca.d1 = wqkvb;
  ca.s2 = Wk; ca.d2 = wqkvb + 1024 * 1024;
  ca.s3 = Wv; ca.d3 = wqkvb + 1280 * 1024;
  ca.s4 = Wo; ca.d4 = wob;
  ca.x = x; ca.Wg = Wg; ca.gate = gateA;
  cvt_all<<<6720, 256, 0, stream>>>(ca);

  gemm_qkv<<<dim3(QKV_N / BN, (B_SZ * T_SZ) / BM), 256, 0, stream>>>(
      xb, wqkvb, ve, cosb, sinb, gateA, qab, kab, vtb);

  attn<<<512, 256, 0, stream>>>(qab, kab, vtb, yb);

  gemm_bt<<<dim3(C_SZ / BN, (B_SZ * T_SZ) / BM), 256, 0, stream>>>(
      yb, wob, out, C_SZ, C_SZ);
}